// Round 1
// 132.732 us; speedup vs baseline: 1.0128x; 1.0128x over previous
//
#include <hip/hip_runtime.h>

#define N_ATOMS 2048
#define NSPEC 7
#define NR 16
#define NFEAT 112          // 7 species * 16 radial shifts; rest of 1008 is zero padding
#define K0P 128            // aev rows padded 112 -> 128 bf16 for MFMA K
#define RCR_F 5.2f
#define H0 256
#define H1 192
#define H2 160
#define W0_PITCH 1008
#define MT 16              // atoms per MLP block (one MFMA m-tile)
#define NTILE16 (N_ATOMS / MT)   // 128 worst-case m-tiles per species

typedef __attribute__((ext_vector_type(8))) short short8;   // 8 bf16 (4 VGPRs)
typedef __attribute__((ext_vector_type(4))) float floatx4;  // MFMA accumulator

// ---- workspace layout (byte offsets into d_ws; poisoned 0xAA each call) ----
// aevb has 2064 rows (16-row slack for m-tile tails; poisoned reads are finite
// bf16 ~ -3e-13 and masked in the energy epilogue)
#define WS_SEG     0          // int[8]
#define WS_SCOORD  16384      // float4[2048]
#define WS_AEVB    65536      // ushort[2064*128]
#define WS_WB0     2621440    // ushort[7*256*128]
#define WS_WB1     3145728    // ushort[7*192*256]
#define WS_WB2     3866624    // ushort[7*160*192]

#define S0E (NSPEC * H0 * K0P)     // 229376
#define S1E (NSPEC * H1 * H0)      // 344064
#define S2E (NSPEC * H2 * H1)      // 215040
#define PREP_TOT (S0E + S1E + S2E) // 788480 = 3080 * 256 exactly

__device__ __forceinline__ float celu01(float x) {
    return x > 0.f ? x : 0.1f * (__expf(x * 10.f) - 1.f);
}

__device__ __forceinline__ unsigned short f2bf(float x) {   // RNE fp32 -> bf16
    unsigned int u = __float_as_uint(x);
    u = (u + 0x7FFFu + ((u >> 16) & 1u)) >> 16;
    return (unsigned short)u;
}

// ---------------- K0: block 0 = counting sort; blocks 1.. = weight bf16 prep ----
__global__ __launch_bounds__(256) void setup_kernel(const int* __restrict__ species,
                                                    const float* __restrict__ coords,
                                                    const float* __restrict__ W0,
                                                    const float* __restrict__ W1,
                                                    const float* __restrict__ W2,
                                                    int* __restrict__ seg,
                                                    float4* __restrict__ scoord,
                                                    unsigned short* __restrict__ wb0,
                                                    unsigned short* __restrict__ wb1,
                                                    unsigned short* __restrict__ wb2,
                                                    float* __restrict__ out) {
    int t = threadIdx.x;
    if (blockIdx.x == 0) {
        __shared__ int cnt[NSPEC];
        __shared__ int cur[NSPEC];
        if (t < NSPEC) cnt[t] = 0;
        __syncthreads();
        for (int a = t; a < N_ATOMS; a += 256) atomicAdd(&cnt[species[a]], 1);
        __syncthreads();
        if (t == 0) {
            int run = 0;
            for (int s = 0; s < NSPEC; s++) { seg[s] = run; cur[s] = run; run += cnt[s]; }
            seg[NSPEC] = run;
            out[0] = 0.0f;   // d_out is poisoned before every call
        }
        __syncthreads();
        for (int a = t; a < N_ATOMS; a += 256) {
            int sp = species[a];
            int pos = atomicAdd(&cur[sp], 1);
            scoord[pos] = make_float4(coords[3*a], coords[3*a+1], coords[3*a+2], 0.f);
        }
    } else {
        int idx = (blockIdx.x - 1) * 256 + t;
        if (idx < S0E) {
            int k = idx & 127, r = idx >> 7;        // r = s*256 + o
            float v = (k < NFEAT) ? W0[(size_t)r * W0_PITCH + k] : 0.f;
            wb0[idx] = f2bf(v);
        } else if (idx < S0E + S1E) {
            wb1[idx - S0E] = f2bf(W1[idx - S0E]);
        } else {
            wb2[idx - S0E - S1E] = f2bf(W2[idx - S0E - S1E]);
        }
    }
}

// ---------------- K1: pair-parallel radial AEV -> bf16 rows of 128 ----------------
// Grid (512, 7), 256 thr = 4 waves; wave w owns (atom p = bx*4+w, species by):
// 64 lanes walk the species segment lane-strided (coalesced).
// exp(-eta*u^2) computed as 2^(ceta*u^2) via raw v_exp_f32 (one less mul per
// Gaussian); fc cos via v_cos_f32 in revolutions (arg in [0,0.5], no reduction).
// Reduction: 4-round value-merge butterfly (17 swizzles total vs 96 for the
// per-value 6-round version), then one coalesced 32B store by lanes 0-15.
__global__ __launch_bounds__(256) void aev_kernel(const float4* __restrict__ scoord,
                                                  const int* __restrict__ seg,
                                                  const float* __restrict__ ShfR,
                                                  const float* __restrict__ EtaR,
                                                  unsigned short* __restrict__ aevb) {
    int s = blockIdx.y;
    int p = blockIdx.x * 4 + (threadIdx.x >> 6);
    int lane = threadIdx.x & 63;

    float4 ci = scoord[p];
    float eta = EtaR[0];
    const float ceta = -eta * 1.44269504089f;     // exp(-eta u^2) = 2^(ceta*u^2)
    float shf[NR];
#pragma unroll
    for (int r = 0; r < NR; r++) shf[r] = ShfR[r];
    float acc[NR];
#pragma unroll
    for (int r = 0; r < NR; r++) acc[r] = 0.f;

    int kbeg = seg[s] + lane;
    int kend = seg[s + 1];
    const float rc2 = RCR_F * RCR_F;
    const float cosk = 0.5f / RCR_F;              // cos(pi*d/Rc) = cos_rev(d/(2Rc))

    for (int k = kbeg; k < kend; k += 64) {
        float4 cj = scoord[k];
        float dx = ci.x - cj.x, dy = ci.y - cj.y, dz = ci.z - cj.z;
        float dsq = fmaf(dx, dx, fmaf(dy, dy, dz * dz));
        bool valid = (dsq > 0.f) && (dsq <= rc2);
        float d = sqrtf(dsq);
        float cr;
        asm("v_cos_f32 %0, %1" : "=v"(cr) : "v"(d * cosk));   // rev in [0,~1], in HW range
        float fc = valid ? fmaf(0.5f, cr, 0.5f) : 0.f;
#pragma unroll
        for (int r = 0; r < NR; r++) {
            float u = d - shf[r];
            float a = ceta * (u * u);
            float e;
            asm("v_exp_f32 %0, %1" : "=v"(e) : "v"(a));       // 2^a; underflow -> 0, fine
            acc[r] = fmaf(e, fc, acc[r]);
        }
    }

    // ---- value-merge butterfly: 16 values/lane -> 1 value/lane ----
    // Round with distance D merges value pairs (2i,2i+1) using lane bit D:
    // lo lane keeps 2i & receives partner's 2i; hi keeps 2i+1 & receives 2i+1.
    // After rounds D=1,2,4,8 slot0 holds original index r == (lane&15), summed
    // over the 16-lane group; xor16/xor32 finish the sum over all 64 lanes.
#define MERGE_ROUND(D, NV)                                            \
    {                                                                 \
        bool hi = (lane & (D)) != 0;                                  \
        _Pragma("unroll")                                             \
        for (int i = 0; i < (NV) / 2; i++) {                          \
            float a = acc[2 * i], b = acc[2 * i + 1];                 \
            float send = hi ? a : b;                                  \
            float keep = hi ? b : a;                                  \
            acc[i] = keep + __shfl_xor(send, (D));                    \
        }                                                             \
    }
    MERGE_ROUND(1, 16)
    MERGE_ROUND(2, 8)
    MERGE_ROUND(4, 4)
    MERGE_ROUND(8, 2)
#undef MERGE_ROUND
    float v = acc[0];
    v += __shfl_xor(v, 16);
    v += __shfl_xor(v, 32);

    unsigned short* dst = aevb + (size_t)p * K0P + s * NR;
    if (lane < NR) {
        dst[lane] = f2bf(v);                       // 16 lanes, one 32B transaction
    } else if (s == 0 && lane < NR + (K0P - NFEAT)) {
        aevb[(size_t)p * K0P + NFEAT + (lane - NR)] = 0;   // zero the pad in parallel
    }
}

// ---------------- K2: fused 3-layer MFMA MLP + energy, one block = 16 atoms ----
// Grid (NTILE16, NSPEC), 512 threads = 8 waves (2 waves/SIMD for latency
// hiding on the global B-operand loads; the kernel is latency-bound with only
// ~135 live blocks). Wave w handles n-tiles nt = it*8+w of each layer.
// A-frags from LDS ([16][K+8] padded rows, 16B aligned); B (weights, bf16)
// streamed from global/L2. MFMA mappings per m89/m101: A[m=lane&15][k=quad*8+j],
// B[n=lane&15][k=...], D col=lane&15, row=quad*4+reg. Activations never touch
// global; energy via 8 atomicAdds.
__global__ __launch_bounds__(512) void mlp_fused(const unsigned short* __restrict__ aevb,
                                                 const unsigned short* __restrict__ wb0,
                                                 const unsigned short* __restrict__ wb1,
                                                 const unsigned short* __restrict__ wb2,
                                                 const float* __restrict__ b0,
                                                 const float* __restrict__ b1,
                                                 const float* __restrict__ b2,
                                                 const float* __restrict__ Wf,
                                                 const float* __restrict__ bf,
                                                 const int* __restrict__ seg,
                                                 float* __restrict__ out) {
    __shared__ unsigned short aevs[MT][K0P + 8];   // rows 272B (17x16B aligned)
    __shared__ unsigned short h0s[MT][H0 + 8];     // rows 528B
    __shared__ unsigned short h1s[MT][H1 + 8];     // rows 400B

    int s = blockIdx.y;                            // species
    int segend = seg[s + 1];
    int base = seg[s] + blockIdx.x * MT;
    if (base >= segend) return;                    // block-uniform
    int n_act = min(MT, segend - base);

    int t = threadIdx.x;
    int w = t >> 6, lane = t & 63;
    int r = lane & 15, quad = lane >> 4;

    // ---- stage AEV tile: first 256 threads x one 16B piece ----
    if (t < 256) {
        int row = t >> 4, chunk = t & 15;          // 16 rows x 16 chunks of 8 shorts
        const short8* src = (const short8*)(aevb + (size_t)(base + row) * K0P + chunk * 8);
        *(short8*)&aevs[row][chunk * 8] = *src;
    }
    __syncthreads();

    // ---- layer0: aev[128] -> h0[256], 16 n-tiles over 8 waves ----
#pragma unroll
    for (int it = 0; it < 2; it++) {
        int nbase = (it * 8 + w) * 16;
        const unsigned short* brow = wb0 + ((size_t)(s * H0 + nbase + r)) * K0P + quad * 8;
        floatx4 acc = {0.f, 0.f, 0.f, 0.f};
#pragma unroll
        for (int ks = 0; ks < K0P / 32; ks++) {
            short8 a = *(const short8*)&aevs[r][ks * 32 + quad * 8];
            short8 b = *(const short8*)(brow + ks * 32);
            acc = __builtin_amdgcn_mfma_f32_16x16x32_bf16(a, b, acc, 0, 0, 0);
        }
        float bi = b0[s * H0 + nbase + r];
#pragma unroll
        for (int reg = 0; reg < 4; reg++)
            h0s[quad * 4 + reg][nbase + r] = f2bf(celu01(acc[reg] + bi));
    }
    __syncthreads();

    // ---- layer1: h0[256] -> h1[192], 12 n-tiles over 8 waves ----
#pragma unroll
    for (int it = 0; it < 2; it++) {
        int nt = it * 8 + w;
        if (nt < H1 / 16) {
            int nbase = nt * 16;
            const unsigned short* brow = wb1 + ((size_t)(s * H1 + nbase + r)) * H0 + quad * 8;
            floatx4 acc = {0.f, 0.f, 0.f, 0.f};
#pragma unroll
            for (int ks = 0; ks < H0 / 32; ks++) {
                short8 a = *(const short8*)&h0s[r][ks * 32 + quad * 8];
                short8 b = *(const short8*)(brow + ks * 32);
                acc = __builtin_amdgcn_mfma_f32_16x16x32_bf16(a, b, acc, 0, 0, 0);
            }
            float bi = b1[s * H1 + nbase + r];
#pragma unroll
            for (int reg = 0; reg < 4; reg++)
                h1s[quad * 4 + reg][nbase + r] = f2bf(celu01(acc[reg] + bi));
        }
    }
    __syncthreads();

    // ---- layer2 + final dot: h1[192] -> 160 outputs, 10 n-tiles over 8 waves ----
    float e = 0.f;
#pragma unroll
    for (int it = 0; it < 2; it++) {
        int nt = it * 8 + w;
        if (nt < H2 / 16) {
            int nbase = nt * 16;
            const unsigned short* brow = wb2 + ((size_t)(s * H2 + nbase + r)) * H1 + quad * 8;
            floatx4 acc = {0.f, 0.f, 0.f, 0.f};
#pragma unroll
            for (int ks = 0; ks < H1 / 32; ks++) {
                short8 a = *(const short8*)&h1s[r][ks * 32 + quad * 8];
                short8 b = *(const short8*)(brow + ks * 32);
                acc = __builtin_amdgcn_mfma_f32_16x16x32_bf16(a, b, acc, 0, 0, 0);
            }
            float bi = b2[s * H2 + nbase + r];
            float wf = Wf[s * H2 + nbase + r];
#pragma unroll
            for (int reg = 0; reg < 4; reg++) {
                int atom = base + quad * 4 + reg;
                if (atom < segend) e += wf * celu01(acc[reg] + bi);
            }
        }
    }
    if (t == 0) e += (float)n_act * bf[s];   // final-layer bias, once per atom

    // wave reduce, one atomic per wave (8/block)
    e += __shfl_xor(e, 1);
    e += __shfl_xor(e, 2);
    e += __shfl_xor(e, 4);
    e += __shfl_xor(e, 8);
    e += __shfl_xor(e, 16);
    e += __shfl_xor(e, 32);
    if (lane == 0) atomicAdd(out, e);
}

extern "C" void kernel_launch(void* const* d_in, const int* in_sizes, int n_in,
                              void* d_out, int out_size, void* d_ws, size_t ws_size,
                              hipStream_t stream) {
    const int*   species = (const int*)d_in[0];
    const float* coords  = (const float*)d_in[1];
    const float* EtaR    = (const float*)d_in[2];
    const float* ShfR    = (const float*)d_in[3];
    const float* W0      = (const float*)d_in[4];
    const float* b0      = (const float*)d_in[5];
    const float* W1      = (const float*)d_in[6];
    const float* b1      = (const float*)d_in[7];
    const float* W2      = (const float*)d_in[8];
    const float* b2      = (const float*)d_in[9];
    const float* Wf      = (const float*)d_in[10];
    const float* bf      = (const float*)d_in[11];
    float* out = (float*)d_out;
    char* ws = (char*)d_ws;

    int*            seg    = (int*)(ws + WS_SEG);
    float4*         scoord = (float4*)(ws + WS_SCOORD);
    unsigned short* aevb   = (unsigned short*)(ws + WS_AEVB);
    unsigned short* wb0    = (unsigned short*)(ws + WS_WB0);
    unsigned short* wb1    = (unsigned short*)(ws + WS_WB1);
    unsigned short* wb2    = (unsigned short*)(ws + WS_WB2);

    hipLaunchKernelGGL(setup_kernel, dim3(1 + PREP_TOT / 256), dim3(256), 0, stream,
                       species, coords, W0, W1, W2, seg, scoord, wb0, wb1, wb2, out);
    hipLaunchKernelGGL(aev_kernel, dim3(N_ATOMS / 4, NSPEC), dim3(256), 0, stream,
                       scoord, seg, ShfR, EtaR, aevb);
    hipLaunchKernelGGL(mlp_fused, dim3(NTILE16, NSPEC), dim3(512), 0, stream,
                       aevb, wb0, wb1, wb2, b0, b1, b2, Wf, bf, seg, out);
}